// Round 1
// baseline (435.237 us; speedup 1.0000x reference)
//
#include <hip/hip_runtime.h>
#include <stdint.h>

#define N_K   10000
#define CIN   3
#define SEQ   1000
#define BATCH 16
#define KM    11
#define NBUCKET 3072

#define NJJ 32   // kernels per block
#define NB  4    // batches per block

typedef _Float16 h2 __attribute__((ext_vector_type(2)));

// ---------------- counting sort of kernel indices by out_len (descending) ----
__global__ __launch_bounds__(1024) void sort_kernel(const int* __restrict__ out_len,
                                                    int* __restrict__ sorted_idx) {
    __shared__ int ha[NBUCKET];
    __shared__ int hb[NBUCKET];
    const int tid = threadIdx.x;
    for (int i = tid; i < NBUCKET; i += 1024) ha[i] = 0;
    __syncthreads();
    for (int j = tid; j < N_K; j += 1024) {
        int key = (NBUCKET - 1) - min(out_len[j], NBUCKET - 1);  // descending
        atomicAdd(&ha[key], 1);
    }
    __syncthreads();
    // Hillis-Steele inclusive scan, ping-pong
    int* cur = ha;
    int* oth = hb;
    for (int off = 1; off < NBUCKET; off <<= 1) {
        for (int i = tid; i < NBUCKET; i += 1024) {
            int v = cur[i];
            if (i >= off) v += cur[i - off];
            oth[i] = v;
        }
        __syncthreads();
        int* t = cur; cur = oth; oth = t;
    }
    // exclusive scan into oth
    for (int i = tid; i < NBUCKET; i += 1024) oth[i] = (i == 0) ? 0 : cur[i - 1];
    __syncthreads();
    for (int j = tid; j < N_K; j += 1024) {
        int key = (NBUCKET - 1) - min(out_len[j], NBUCKET - 1);
        int pos = atomicAdd(&oth[key], 1);
        sorted_idx[pos] = j;
    }
}

// ---------------- main kernel ------------------------------------------------
// block = 256 threads = 32 j-slots x 4 batches x 2 t-halves
// lane layout: h = tid&1, lb = (tid>>1)&3, jj = tid>>3  -> 8 consecutive sorted
// kernels per wave (similar out_len -> minimal loop-trip divergence).
__global__ __launch_bounds__(256) void rocket_kernel(
    const float* __restrict__ x, const float* __restrict__ w,
    const float* __restrict__ bias, const int* __restrict__ dil,
    const int* __restrict__ start, const int* __restrict__ out_len,
    const int* __restrict__ pad_max_p, const int* __restrict__ sorted_idx,
    float* __restrict__ out) {
    // per position: (c0,c1,c2,0) packed fp16, sentinel zero rows at pos -1 / 1000
    __shared__ unsigned long long xs[NB * 1002];

    const int tid = threadIdx.x;
    const int h  = tid & 1;
    const int lb = (tid >> 1) & 3;
    const int jj = tid >> 3;
    const int bg = blockIdx.x & 3;        // batch group (4 groups of 4)
    const int jg = blockIdx.x >> 2;       // kernel group

    // ---- stage x (4 batches) into LDS as packed fp16 -----------------------
    for (int lbb = 0; lbb < NB; ++lbb) {
        const float* xb = x + (size_t)(bg * NB + lbb) * (CIN * SEQ);
        for (int pos = tid; pos < SEQ; pos += 256) {
            float a0 = xb[pos];
            float a1 = xb[SEQ + pos];
            float a2 = xb[2 * SEQ + pos];
            unsigned u0 = (unsigned)__builtin_bit_cast(unsigned short, (_Float16)a0);
            unsigned u1 = (unsigned)__builtin_bit_cast(unsigned short, (_Float16)a1);
            unsigned u2 = (unsigned)__builtin_bit_cast(unsigned short, (_Float16)a2);
            xs[lbb * 1002 + 1 + pos] =
                (unsigned long long)(u0 | (u1 << 16)) | ((unsigned long long)u2 << 32);
        }
    }
    if (tid < NB * 2) xs[(tid >> 1) * 1002 + (tid & 1) * 1001] = 0ULL;  // sentinels
    __syncthreads();

    const int ji = jg * NJJ + jj;
    if (ji >= N_K) return;
    const int j = sorted_idx[ji];

    const int d   = dil[j];
    const int ol  = out_len[j];
    const int off = start[j] - pad_max_p[0];
    const float bj = bias[j];
    const float* wj = w + (size_t)j * (CIN * KM);

    // effective kernel size (padding taps are exactly 0.0f)
    int ks = 1;
#pragma unroll
    for (int k = 1; k < KM; ++k) {
        if (wj[k] != 0.f || wj[KM + k] != 0.f || wj[2 * KM + k] != 0.f) ks = k + 1;
    }

    h2 wl[KM], wh[KM];
#pragma unroll
    for (int k = 0; k < KM; ++k) {
        h2 a, b;
        a.x = (_Float16)wj[k];
        a.y = (_Float16)wj[KM + k];
        b.x = (_Float16)wj[2 * KM + k];
        b.y = (_Float16)0.f;
        wl[k] = a;
        wh[k] = b;
    }

    const int base = lb * 1002;
    int idx0[KM];
#pragma unroll
    for (int k = 0; k < KM; ++k) idx0[k] = base + 1 + off + min(k, ks - 1) * d;
    const int lo = base;          // sentinel zero (pos -1)
    const int hi = base + 1001;   // sentinel zero (pos 1000)

    float mx = -3.4e38f;
    int cnt = 0;
    const int t0 = h * ((ol + 1) >> 1);
    const int t1 = h ? ol : ((ol + 1) >> 1);

#pragma unroll 2
    for (int t = t0; t < t1; ++t) {
        float acc0 = 0.f, acc1 = 0.f;
#pragma unroll
        for (int k = 0; k < KM; ++k) {
            int p = idx0[k] + t;
            p = min(max(p, lo), hi);          // v_med3_i32
            unsigned long long v = xs[p];     // ds_read_b64: (c0,c1) | (c2,0)
            h2 xl = __builtin_bit_cast(h2, (unsigned)v);
            h2 xh = __builtin_bit_cast(h2, (unsigned)(v >> 32));
            acc0 = __builtin_amdgcn_fdot2(xl, wl[k], acc0, false);
            acc1 = __builtin_amdgcn_fdot2(xh, wh[k], acc1, false);
        }
        float val = acc0 + acc1 + bj;
        mx = fmaxf(mx, val);
        cnt += (val > 0.f) ? 1 : 0;
    }

    // combine the two t-halves (adjacent lanes)
    float mo = __shfl_xor(mx, 1);
    int   co = __shfl_xor(cnt, 1);
    mx = fmaxf(mx, mo);
    cnt += co;

    if (h == 0) {
        float2 r;
        r.x = mx;
        r.y = (float)cnt / (float)ol;
        *(float2*)(out + (size_t)(bg * NB + lb) * (2 * N_K) + 2 * j) = r;
    }
}

extern "C" void kernel_launch(void* const* d_in, const int* in_sizes, int n_in,
                              void* d_out, int out_size, void* d_ws, size_t ws_size,
                              hipStream_t stream) {
    const float* x       = (const float*)d_in[0];
    const float* weight  = (const float*)d_in[1];
    const float* bias    = (const float*)d_in[2];
    const int*   dil     = (const int*)d_in[3];
    const int*   start   = (const int*)d_in[4];
    const int*   out_len = (const int*)d_in[5];
    const int*   pad_max = (const int*)d_in[6];
    (void)in_sizes; (void)n_in; (void)out_size; (void)ws_size;

    int* sorted_idx = (int*)d_ws;  // 10000 ints

    sort_kernel<<<1, 1024, 0, stream>>>(out_len, sorted_idx);

    const int jgroups = (N_K + NJJ - 1) / NJJ;  // 313
    rocket_kernel<<<jgroups * 4, 256, 0, stream>>>(
        x, weight, bias, dil, start, out_len, pad_max, sorted_idx, (float*)d_out);
}